// Round 11
// baseline (67.981 us; speedup 1.0000x reference)
//
#include <hip/hip_runtime.h>
#include <cstdint>
#include <cstddef>

typedef _Float16 f16x8 __attribute__((ext_vector_type(8)));
typedef _Float16 f16x4 __attribute__((ext_vector_type(4)));
typedef float    f32x16 __attribute__((ext_vector_type(16)));

#define MFMA32(a,b,c) __builtin_amdgcn_mfma_f32_32x32x16_f16((a),(b),(c),0,0,0)

// ws layout (halfs) — weights pre-swizzled into MFMA fragment-linear order:
//   W1F  [15][2][16][64][8] @0        (245760)   win*16384 + side*8192 + kk*512 + l*8
//   W16F [2][23][64][8]     @245760   (23552)    x col = 1808+sp, zero sp<12  (sp=16kk+8(l>>5)+j)
//   W2F  [4][2][16][64][8]  @269312   (65536)
//   W3F  [9][16][64][8]     @334848   (73728)    o-sets of 32; o>=260 zero
__global__ void tea_prep(const float* __restrict__ W1, const float* __restrict__ W16,
                         const float* __restrict__ W2, const float* __restrict__ W3,
                         _Float16* __restrict__ ws)
{
    int i = blockIdx.x * blockDim.x + threadIdx.x;
    if (i < 245760) {
        int win = i >> 14, t = i & 16383;
        int side = t >> 13, kk = (t >> 9) & 15, l = (t >> 3) & 63, j = t & 7;
        int o = 32 * side + (l & 31);
        int s = 16 * kk + 8 * (l >> 5) + j;
        ws[i] = (_Float16)W1[(win * 256 + s) * 64 + o];
    } else if (i < 269312) {
        int t = i - 245760;
        int side = t / 11776, t2 = t % 11776;
        int kk = t2 >> 9, l = (t2 >> 3) & 63, j = t2 & 7;
        int o = 32 * side + (l & 31);
        int sp = 16 * kk + 8 * (l >> 5) + j;
        ws[i] = (_Float16)((sp >= 12 && sp < 368) ? W16[(sp - 12) * 64 + o] : 0.f);
    } else if (i < 334848) {
        int t = i - 269312;
        int g = t >> 14, t2 = t & 16383;
        int side = t2 >> 13, kk = (t2 >> 9) & 15, l = (t2 >> 3) & 63, j = t2 & 7;
        int og = 32 * side + (l & 31);
        int s = 16 * kk + 8 * (l >> 5) + j;
        ws[i] = (_Float16)W2[(g * 256 + s) * 64 + og];
    } else if (i < 408576) {
        int t = i - 334848;
        int set = t >> 13;
        int kk = (t >> 9) & 15, l = (t >> 3) & 63, j = t & 7;
        int o = 32 * set + (l & 31);
        int s = 16 * kk + 8 * (l >> 5) + j;
        ws[i] = (_Float16)((o < 260) ? W3[s * 260 + o] : 0.f);
    }
}

// Persistent fused: 256 blocks x 2 row-tiles (32 rows each), 1024 threads, 1 block/CU.
// Tile1's x loads stream in register batches UNDER tile0's compute; all barriers
// are raw lgkmcnt(0)+s_barrier (no vmcnt drain ever).
// LDS map (halfs; sh[69888] = 139776 B):
//   xsm  stride 2184, [0, 69888)     staged x fp16 (dead after l1)
//   ylds stride 1032, [0, 33024)     aliases xsm (post-b1)
//   zlds stride 264,  [33152, 41600)
//   ps   f32 18x320 @half 41600, [41600, 53120)
__global__ __launch_bounds__(1024, 4)
void tea_fused(const float* __restrict__ x,
               const float* __restrict__ b1,  const float* __restrict__ b16,
               const float* __restrict__ b2,  const float* __restrict__ b3,
               const _Float16* __restrict__ ws, float* __restrict__ out)
{
    __shared__ _Float16 sh[69888];
    _Float16* ylds = sh;
    _Float16* zlds = sh + 33152;
    float*    ps   = (float*)(sh + 41600);

    const int tid = threadIdx.x;
    const int bid = blockIdx.x;
    const int wg  = (bid & 7) * 32 + (bid >> 3);      // bijective XCD swizzle (256%8==0)
    const int q = tid >> 6, l = tid & 63, r = l & 31, h = l >> 5;

    const float* xg0 = x + (size_t)(wg * 2 + 0) * 32 * 2176;
    const float* xg1 = x + (size_t)(wg * 2 + 1) * 32 * 2176;

    float4 S[17];

#define BAR() do { \
    asm volatile("s_waitcnt lgkmcnt(0)" ::: "memory"); \
    __builtin_amdgcn_s_barrier(); \
    __builtin_amdgcn_sched_barrier(0); } while (0)

#define LOADX(XG, I) do { \
    if ((I) < 16) { int _e = (I) * 4096 + tid * 4; \
        S[(I)] = *(const float4*)((XG) + (size_t)(_e >> 11) * 2176 + (_e & 2047)); } \
    else { S[16] = *(const float4*)((XG) + (size_t)(tid >> 5) * 2176 + 2048 + (tid & 31) * 4); } } while (0)

#define WRITEX(I) do { \
    float4 _u = S[(I)]; f16x4 _hv; \
    _hv[0] = (_Float16)_u.x; _hv[1] = (_Float16)_u.y; \
    _hv[2] = (_Float16)_u.z; _hv[3] = (_Float16)_u.w; \
    if ((I) < 16) { int _e = (I) * 4096 + tid * 4; \
        *(f16x4*)&sh[(_e >> 11) * 2184 + (_e & 2047)] = _hv; } \
    else { *(f16x4*)&sh[(tid >> 5) * 2184 + 2048 + (tid & 31) * 4] = _hv; } } while (0)

    // process one staged tile; PF=1 -> prefetch xg1 batches during compute
#define TILE_BODY(TROW, PF) do { \
    f32x16 acc0, acc1; \
    _Pragma("unroll") for (int _i = 0; _i < 16; ++_i) { acc0[_i] = 0.f; acc1[_i] = 0.f; } \
    if (PF) { _Pragma("unroll") for (int _i = 0; _i < 6; ++_i) LOADX(xg1, _i); } \
    if (q < 15) { \
        const _Float16* A = ws + q * 16384; \
        const int cb = 128 * q; \
        _Pragma("unroll") for (int kk = 0; kk < 16; ++kk) { \
            f16x8 B  = *(const f16x8*)&sh[r * 2184 + cb + 16 * kk + 8 * h]; \
            f16x8 A0 = *(const f16x8*)(A + kk * 512 + l * 8); \
            f16x8 A1 = *(const f16x8*)(A + 8192 + kk * 512 + l * 8); \
            acc0 = MFMA32(A0, B, acc0); \
            acc1 = MFMA32(A1, B, acc1); } \
    } else { \
        const _Float16* A = ws + 245760; \
        _Pragma("unroll") for (int kk = 0; kk < 23; ++kk) { \
            f16x8 B  = *(const f16x8*)&sh[r * 2184 + 1808 + 16 * kk + 8 * h]; \
            f16x8 A0 = *(const f16x8*)(A + kk * 512 + l * 8); \
            f16x8 A1 = *(const f16x8*)(A + 11776 + kk * 512 + l * 8); \
            acc0 = MFMA32(A0, B, acc0); \
            acc1 = MFMA32(A1, B, acc1); } \
    } \
    BAR(); /* b1: all xsm reads retired */ \
    { \
        const float* bp = (q < 15) ? (b1 + q * 64) : b16; \
        _Pragma("unroll") for (int s = 0; s < 2; ++s) \
            _Pragma("unroll") for (int j = 0; j < 4; ++j) { \
                f16x4 pk; \
                _Pragma("unroll") for (int t = 0; t < 4; ++t) { \
                    float v = (s ? acc1[4 * j + t] : acc0[4 * j + t]) + bp[32 * s + 8 * j + 4 * h + t]; \
                    v = v > 0.f ? v : 0.f; \
                    pk[t] = (_Float16)v; } \
                *(f16x4*)&ylds[r * 1032 + q * 64 + 32 * s + 8 * j + 4 * h] = pk; } \
    } \
    BAR(); /* b2: y published */ \
    if (PF) { _Pragma("unroll") for (int _i = 6; _i < 12; ++_i) LOADX(xg1, _i); } \
    if (q < 8) { \
        const int g = q >> 1, sd = q & 1; \
        const _Float16* A = ws + 269312 + g * 16384 + sd * 8192; \
        f32x16 a; \
        _Pragma("unroll") for (int _i = 0; _i < 16; ++_i) a[_i] = 0.f; \
        _Pragma("unroll") for (int kk = 0; kk < 16; ++kk) { \
            f16x8 B  = *(const f16x8*)&ylds[r * 1032 + 256 * g + 16 * kk + 8 * h]; \
            f16x8 A0 = *(const f16x8*)(A + kk * 512 + l * 8); \
            a = MFMA32(A0, B, a); } \
        const float* bz = b2 + g * 64 + 32 * sd; \
        _Pragma("unroll") for (int j = 0; j < 4; ++j) { \
            f16x4 pk; \
            _Pragma("unroll") for (int t = 0; t < 4; ++t) { \
                float v = a[4 * j + t] + bz[8 * j + 4 * h + t]; \
                v = v > 0.f ? v : 0.f; \
                pk[t] = (_Float16)v; } \
            *(f16x4*)&zlds[r * 264 + g * 64 + sd * 32 + 8 * j + 4 * h] = pk; } \
    } \
    BAR(); /* b3: z published */ \
    if (PF) { _Pragma("unroll") for (int _i = 12; _i < 17; ++_i) LOADX(xg1, _i); } \
    if (q < 9) { \
        const _Float16* A3 = ws + 334848 + q * 8192; \
        f32x16 a; \
        _Pragma("unroll") for (int _i = 0; _i < 16; ++_i) a[_i] = 0.f; \
        _Pragma("unroll") for (int kk = 0; kk < 16; ++kk) { \
            f16x8 B  = *(const f16x8*)&zlds[r * 264 + 16 * kk + 8 * h]; \
            f16x8 A0 = *(const f16x8*)(A3 + kk * 512 + l * 8); \
            a = MFMA32(A0, B, a); } \
        float p[10]; \
        _Pragma("unroll") for (int c = 0; c < 10; ++c) p[c] = 0.f; \
        _Pragma("unroll") for (int m = 0; m < 16; ++m) { \
            int o = 32 * q + (m & 3) + 8 * (m >> 2) + 4 * h; \
            if (o < 260) { \
                float v = a[m] + b3[o]; \
                v = v > 0.f ? v : 0.f; \
                p[(unsigned)o / 26u] += v; } } \
        _Pragma("unroll") for (int c = 0; c < 10; ++c) \
            ps[(q * 2 + h) * 320 + r * 10 + c] = p[c]; \
    } \
    BAR(); /* b4: partials in */ \
    if (tid < 32) { \
        float v[10]; \
        _Pragma("unroll") for (int c = 0; c < 10; ++c) { \
            float s = 0.f; \
            _Pragma("unroll") for (int j = 0; j < 18; ++j) s += ps[j * 320 + tid * 10 + c]; \
            v[c] = s; } \
        float mx = v[0]; \
        _Pragma("unroll") for (int c = 1; c < 10; ++c) mx = fmaxf(mx, v[c]); \
        float e[10], se = 0.f; \
        _Pragma("unroll") for (int c = 0; c < 10; ++c) { e[c] = expf(v[c] - mx); se += e[c]; } \
        float inv = 1.f / se; \
        float* orow = out + (size_t)((TROW) * 32 + tid) * 10; \
        _Pragma("unroll") for (int c = 0; c < 10; ++c) orow[c] = e[c] * inv; \
    } } while (0)

    // ---- stage tile 0 ----
    #pragma unroll
    for (int i = 0; i < 17; ++i) LOADX(xg0, i);
    #pragma unroll
    for (int i = 0; i < 17; ++i) WRITEX(i);
    BAR();                                            // b0: x0 staged

    // ---- tile 0 (prefetching tile 1's x into S) ----
    TILE_BODY(wg * 2 + 0, 1);
    BAR();                                            // b5: ps reads done -> xsm free

    // ---- write tile 1's x (counted vmcnt on ancient loads) ----
    #pragma unroll
    for (int i = 0; i < 17; ++i) WRITEX(i);
    BAR();                                            // b6: x1 staged

    // ---- tile 1 ----
    TILE_BODY(wg * 2 + 1, 0);

#undef BAR
#undef LOADX
#undef WRITEX
#undef TILE_BODY
}

extern "C" void kernel_launch(void* const* d_in, const int* in_sizes, int n_in,
                              void* d_out, int out_size, void* d_ws, size_t ws_size,
                              hipStream_t stream)
{
    const float* x   = (const float*)d_in[0];
    const float* W1  = (const float*)d_in[1];
    const float* b1  = (const float*)d_in[2];
    const float* W16 = (const float*)d_in[3];
    const float* b16 = (const float*)d_in[4];
    const float* W2  = (const float*)d_in[5];
    const float* b2  = (const float*)d_in[6];
    const float* W3  = (const float*)d_in[7];
    const float* b3  = (const float*)d_in[8];
    float*    out = (float*)d_out;
    _Float16* ws  = (_Float16*)d_ws;

    tea_prep <<<1596, 256, 0, stream>>>(W1, W16, W2, W3, ws);
    tea_fused<<<256, 1024, 0, stream>>>(x, b1, b16, b2, b3, ws, out);
}